// Round 6
// baseline (834.367 us; speedup 1.0000x reference)
//
#include <hip/hip_runtime.h>
#include <hip/hip_bf16.h>

#define TB 256
#define TBM 512   // MFMA kernels: 8 waves/block
#define BM 64
#define BK 32
#define BN 128
#define ASTR 68   // BM + 4 (fp32 path, k6)
#define MAXD 160  // per-node edge cache for k5

static constexpr int NN = 20000;
static constexpr int NE = 320000;

// workspace layout (floats)
static constexpr long long OFF_HN   = 0;          // hnH/hnL bf16 split: NN*128 ushorts each
static constexpr long long OFF_OW   = 2560000;    // owH/owL bf16: E*128 ushort each
static constexpr long long OFF_S    = 43520000;   // E  (raw attention scalar s)
static constexpr long long OFF_DEN  = 43840000;   // N
static constexpr long long OFF_CUR  = 43860000;   // N ints
static constexpr long long OFF_HAGG = 43880000;   // N*256 fp32; post-k6 overlaid houtH/L (512-ushort row stride)
static constexpr long long OFF_WT   = 49000000;   // split-bf16 transposed weights (ushort)
static constexpr long long WS_FLOATS = 49140000;  // ~196.6 MB (proven budget)

// Wt sub-offsets in ushort units from OFF_WT base
static constexpr int U_E = 0;        // W_eedge^T hi [128][128]; lo at +16384
static constexpr int U_F = 32768;    // W_fuse^T  hi [128][384]; lo at +49152
static constexpr int U_A = 131072;   // W_aggre^T hi [128][512]; lo at +65536

// d_out layout (floats): h_out, w_out, sat
static constexpr long long OUT_HOUT = 0;
static constexpr long long OUT_WOUT = 2560000;    // holds w2 until k7 overwrites with w_out
static constexpr long long OUT_SAT  = 43520000;

typedef __attribute__((ext_vector_type(8))) short s8v;            // 8 bf16 (4 VGPR)
typedef __attribute__((ext_vector_type(4))) float f32x4;
typedef __attribute__((ext_vector_type(8))) unsigned short u16x8;
typedef __attribute__((ext_vector_type(4))) unsigned short u16x4;

#define MFMA16(a,b,c) __builtin_amdgcn_mfma_f32_16x16x32_bf16(a,b,c,0,0,0)

__device__ __forceinline__ float lrelu(float x){ return x >= 0.f ? x : 0.1f*x; }

// async global->LDS, 16B per lane; LDS dest = wave-uniform base + lane*16
__device__ __forceinline__ void gl16(const void* g, void* l){
    __builtin_amdgcn_global_load_lds(
        (const __attribute__((address_space(1))) void*)g,
        (__attribute__((address_space(3))) void*)l, 16, 0, 0);
}

// ---- split fp32 -> (hi,lo) bf16, RNE both ----
__device__ __forceinline__ void split1(float f, unsigned short& hi, unsigned short& lo){
    __hip_bfloat16 h = __float2bfloat16(f);
    float hf = __bfloat162float(h);
    __hip_bfloat16 l = __float2bfloat16(f - hf);
    hi = __builtin_bit_cast(unsigned short, h);
    lo = __builtin_bit_cast(unsigned short, l);
}
__device__ __forceinline__ void split8(float4 a, float4 b, s8v& hi, s8v& lo){
    float v[8] = {a.x,a.y,a.z,a.w,b.x,b.y,b.z,b.w};
#pragma unroll
    for (int j = 0; j < 8; ++j){
        unsigned short hs, ls;
        split1(v[j], hs, ls);
        hi[j] = (short)hs; lo[j] = (short)ls;
    }
}
__device__ __forceinline__ float bfpair(unsigned short h, unsigned short l){
    return __uint_as_float(((unsigned)h)<<16) + __uint_as_float(((unsigned)l)<<16);
}

// LDS tile addressing: [128 rows][32 k] bf16; slot g holds k-group g^(row&3)
__device__ __forceinline__ int lds_a(int row, int g){
    return row*32 + ((g ^ (row & 3)) << 3);   // ushort index, 16B aligned
}

// ================= fp32 helpers for k6 =================
__device__ __forceinline__ void store_At(float (*Ast)[ASTR], int k4, int r, float4 v){
    Ast[k4+0][r] = v.x; Ast[k4+1][r] = v.y; Ast[k4+2][r] = v.z; Ast[k4+3][r] = v.w;
}
__device__ __forceinline__ void mm_chunk(const float (*Ast)[ASTR], const float (*Bs)[BN],
                                         int r0, int c0, float acc[4][8]){
#pragma unroll 4
    for (int k = 0; k < BK; ++k){
        const float4 av = *(const float4*)&Ast[k][r0];
        const float4 b0 = *(const float4*)&Bs[k][c0];
        const float4 b1 = *(const float4*)&Bs[k][64 + c0];
        const float a0=av.x, a1=av.y, a2=av.z, a3=av.w;
        const float b[8] = {b0.x,b0.y,b0.z,b0.w,b1.x,b1.y,b1.z,b1.w};
#pragma unroll
        for (int j = 0; j < 8; ++j){
            acc[0][j] = fmaf(a0, b[j], acc[0][j]);
            acc[1][j] = fmaf(a1, b[j], acc[1][j]);
            acc[2][j] = fmaf(a2, b[j], acc[2][j]);
            acc[3][j] = fmaf(a3, b[j], acc[3][j]);
        }
    }
}
__device__ __forceinline__ void load_B(const float* __restrict__ W, int kc,
                                       float (*Bs)[BN], int tid){
#pragma unroll
    for (int p = 0; p < 4; ++p){
        int idx = p*TB + tid;
        int row = idx >> 5;
        int c4  = (idx & 31) << 2;
        *(float4*)&Bs[row][c4] = *(const float4*)&W[(size_t)(kc+row)*BN + c4];
    }
}

// block-wide reductions (k5)
__device__ __forceinline__ float blockMax(float v, float* sh4){
#pragma unroll
    for (int m = 32; m; m >>= 1) v = fmaxf(v, __shfl_xor(v, m));
    if ((threadIdx.x & 63) == 0) sh4[threadIdx.x >> 6] = v;
    __syncthreads();
    float r = fmaxf(fmaxf(sh4[0], sh4[1]), fmaxf(sh4[2], sh4[3]));
    __syncthreads();
    return r;
}
__device__ __forceinline__ float blockSum(float v, float* sh4){
#pragma unroll
    for (int m = 32; m; m >>= 1) v += __shfl_xor(v, m);
    if ((threadIdx.x & 63) == 0) sh4[threadIdx.x >> 6] = v;
    __syncthreads();
    float r = sh4[0] + sh4[1] + sh4[2] + sh4[3];
    __syncthreads();
    return r;
}

// ---------------- k_prep: cur init + all three weight transpose/splits ----------------
__global__ __launch_bounds__(TB) void k_prep(const float* __restrict__ We,
                                             const float* __restrict__ Wf,
                                             const float* __restrict__ Wa,
                                             unsigned short* __restrict__ wt,
                                             int* __restrict__ cur){
    int id = blockIdx.x*TB + threadIdx.x;   // grid covers 131072
    if (id < NN) cur[id] = 0;
    unsigned short hs, ls;
    if (id < 16384){                       // W_eedge: K=128
        int n = id >> 7, k = id & 127;
        split1(We[(size_t)k*128 + n], hs, ls);
        wt[U_E + id] = hs; wt[U_E + 16384 + id] = ls;
    } else if (id < 65536){                // W_fuse: K=384
        int local = id - 16384;
        int n = local / 384, k = local - n*384;
        split1(Wf[(size_t)k*128 + n], hs, ls);
        wt[U_F + local] = hs; wt[U_F + 49152 + local] = ls;
    } else if (id < 131072){               // W_aggre: K=512
        int local = id - 65536;
        int n = local >> 9, k = local & 511;
        split1(Wa[(size_t)k*128 + n], hs, ls);
        wt[U_A + local] = hs; wt[U_A + 65536 + local] = ls;
    }
}

// ---------------- sort pipeline ----------------
__global__ __launch_bounds__(TB) void kB_count(const int* __restrict__ dst,
                                               int* __restrict__ cur){
    int e = blockIdx.x*TB + threadIdx.x;
    atomicAdd(&cur[dst[e]], 1);
}
__global__ __launch_bounds__(TB) void kC_scan(int* __restrict__ cur,
                                              int* __restrict__ offs){
    __shared__ int part[TB];
    __shared__ int spre[TB];
    const int tid = threadIdx.x;
    const int CH = (NN + TB - 1) / TB;
    const int base = tid * CH;
    int sum = 0;
    for (int i = 0; i < CH; ++i){ int idx = base + i; if (idx < NN) sum += cur[idx]; }
    part[tid] = sum;
    __syncthreads();
    if (tid == 0){ int r = 0; for (int i = 0; i < TB; ++i){ spre[i] = r; r += part[i]; } }
    __syncthreads();
    int run = spre[tid];
    for (int i = 0; i < CH; ++i){
        int idx = base + i;
        if (idx < NN){ int c = cur[idx]; offs[idx] = run; cur[idx] = run; run += c; }
    }
}
__global__ __launch_bounds__(TB) void kD_scatter(const int* __restrict__ dst,
                                                 int* __restrict__ cur,
                                                 int* __restrict__ eidx){
    int e = blockIdx.x*TB + threadIdx.x;
    int p = atomicAdd(&cur[dst[e]], 1);
    eidx[p] = e;
}

// ---------------- k1: hn = h @ W_node (fp32 GEMM, bf16-split output) ----------------
__global__ __launch_bounds__(TB) void k1_hn(const float* __restrict__ h,
                                            const float* __restrict__ Wn,
                                            unsigned short* __restrict__ hnH,
                                            unsigned short* __restrict__ hnL){
    __shared__ float Ast[BK][ASTR];
    __shared__ float Bs[BK][BN];
    const int tid = threadIdx.x;
    const int rbase = blockIdx.x * BM;
    const int tc = tid & 15, tr = tid >> 4;
    const int r0 = tr*4, c0 = tc*4;
    float acc[4][8] = {};
    for (int kc = 0; kc < 128; kc += BK){
        __syncthreads();
        {
            int lr = tid >> 3, k4 = (tid & 7) << 2;
#pragma unroll
            for (int p = 0; p < 2; ++p){
                int r = p*32 + lr;
                int rr = rbase + r; if (rr >= NN) rr = NN-1;
                float4 v = *(const float4*)&h[(size_t)rr*128 + kc + k4];
                store_At(Ast, k4, r, v);
            }
        }
        load_B(Wn, kc, Bs, tid);
        __syncthreads();
        mm_chunk(Ast, Bs, r0, c0, acc);
    }
#pragma unroll
    for (int i = 0; i < 4; ++i){
        int rr = rbase + r0 + i;
        if (rr < NN){
            u16x4 h0, l0, h1, l1;
#pragma unroll
            for (int j = 0; j < 4; ++j){
                unsigned short hs, ls;
                split1(acc[i][j], hs, ls);   h0[j] = hs; l0[j] = ls;
                split1(acc[i][4+j], hs, ls); h1[j] = hs; l1[j] = ls;
            }
            *(u16x4*)&hnH[(size_t)rr*128 + c0] = h0;
            *(u16x4*)&hnL[(size_t)rr*128 + c0] = l0;
            *(u16x4*)&hnH[(size_t)rr*128 + 64 + c0] = h1;
            *(u16x4*)&hnL[(size_t)rr*128 + 64 + c0] = l1;
        }
    }
}

// ================== MFMA split-bf16 edge GEMMs: 512 thr, 8 waves, 128x128 tile ==================
// double-buffered LDS, 1 barrier/K-step; B (and pre-split A groups) staged via global_load_lds

// ---------------- k2: ow = edge_w @ W_eedge ; w1 = (lrelu(ow)@W_esf)*ow ----------------
__global__ __launch_bounds__(TBM) void k2_mfma(const float* __restrict__ ew,
                                               const unsigned short* __restrict__ wtH,
                                               const unsigned short* __restrict__ wtL,
                                               const float* __restrict__ Wesf,
                                               unsigned short* __restrict__ owH,
                                               unsigned short* __restrict__ owL,
                                               float* __restrict__ sat){
    __shared__ __align__(16) unsigned short Ah[2][4096], Al[2][4096], Bh[2][4096], Bl[2][4096];
    __shared__ float sEsf[128];
    const int tid = threadIdx.x;
    const long long rbase = (long long)blockIdx.x * 128;
    const int lane = tid & 63, w = tid >> 6;
    const int ls = lane & 15, lg = lane >> 4;
    const int srow = tid >> 2, sg = tid & 3;
    const int gsw = sg ^ (srow & 3);
    const int aslot = srow*32 + (gsw << 3);
    if (tid < 128) sEsf[tid] = Wesf[tid];
    f32x4 acc[8] = {};
    auto stage = [&](int nb, int t){
        const int kc = t*32;
        gl16(&wtH[srow*128 + kc + gsw*8], &Bh[nb][w*512]);
        gl16(&wtL[srow*128 + kc + gsw*8], &Bl[nb][w*512]);
        const float* p = &ew[(rbase + srow)*128 + kc + sg*8];
        float4 v0 = *(const float4*)p, v1 = *(const float4*)(p+4);
        s8v hi, lo; split8(v0, v1, hi, lo);
        *(s8v*)&Ah[nb][aslot] = hi; *(s8v*)&Al[nb][aslot] = lo;
    };
    stage(0, 0);
    __syncthreads();
    int cur = 0;
    for (int t = 0; t < 4; ++t){
        if (t+1 < 4) stage(cur^1, t+1);
        s8v ah = *(const s8v*)&Ah[cur][lds_a(w*16 + ls, lg)];
        s8v al = *(const s8v*)&Al[cur][lds_a(w*16 + ls, lg)];
#pragma unroll
        for (int ct = 0; ct < 8; ++ct){
            int c = ct*16 + ls;
            s8v bh = *(const s8v*)&Bh[cur][lds_a(c,lg)];
            s8v bl = *(const s8v*)&Bl[cur][lds_a(c,lg)];
            acc[ct] = MFMA16(ah, bh, acc[ct]);
            acc[ct] = MFMA16(ah, bl, acc[ct]);
            acc[ct] = MFMA16(al, bh, acc[ct]);
        }
        __syncthreads();
        cur ^= 1;
    }
#pragma unroll
    for (int reg = 0; reg < 4; ++reg){
        float p = 0.f;
#pragma unroll
        for (int ct = 0; ct < 8; ++ct)
            p += lrelu(acc[ct][reg]) * sEsf[ct*16 + ls];
#pragma unroll
        for (int m = 1; m < 16; m <<= 1) p += __shfl_xor(p, m);
        long long orow = rbase + w*16 + lg*4 + reg;
#pragma unroll
        for (int ct = 0; ct < 8; ++ct){
            float o = acc[ct][reg];
            int col = ct*16 + ls;
            sat[orow*384 + 256 + col] = p * o;
            unsigned short hs_, ls_; split1(o, hs_, ls_);
            owH[orow*128 + col] = hs_;
            owL[orow*128 + col] = ls_;
        }
    }
}

// ---------------- k3: sat build + inw GEMM + attn dot + w2 + s ----------------
__global__ __launch_bounds__(TBM) void k3_mfma(const unsigned short* __restrict__ hnH,
                                               const unsigned short* __restrict__ hnL,
                                               const unsigned short* __restrict__ wtH,
                                               const unsigned short* __restrict__ wtL,
                                               const float* __restrict__ bf,
                                               const float* __restrict__ Wattn,
                                               const int* __restrict__ src,
                                               const int* __restrict__ dst,
                                               float* __restrict__ sat,
                                               float* __restrict__ w2,
                                               float* __restrict__ s_ws){
    __shared__ __align__(16) unsigned short Ah[2][4096], Al[2][4096], Bh[2][4096], Bl[2][4096];
    __shared__ float sBf[128], sAtt[128];
    __shared__ int sSrc[128], sDst[128];
    const int tid = threadIdx.x;
    const long long rbase = (long long)blockIdx.x * 128;
    const int lane = tid & 63, w = tid >> 6;
    const int ls = lane & 15, lg = lane >> 4;
    const int srow = tid >> 2, sg = tid & 3;
    const int gsw = sg ^ (srow & 3);
    const int aslot = srow*32 + (gsw << 3);
    if (tid < 128){
        sBf[tid] = bf[tid]; sAtt[tid] = Wattn[tid];
        sSrc[tid] = src[rbase + tid]; sDst[tid] = dst[rbase + tid];
    }
    __syncthreads();   // sSrc/sDst used by stage
    f32x4 acc[8] = {};
    auto stage = [&](int nb, int t){
        const int kc = t*32;
        gl16(&wtH[srow*384 + kc + gsw*8], &Bh[nb][w*512]);
        gl16(&wtL[srow*384 + kc + gsw*8], &Bl[nb][w*512]);
        long long e = rbase + srow;
        if (kc < 256){
            int node = (kc < 128) ? sSrc[srow] : sDst[srow];
            int col0 = kc & 127;
            gl16(&hnH[(size_t)node*128 + col0 + gsw*8], &Ah[nb][w*512]);
            gl16(&hnL[(size_t)node*128 + col0 + gsw*8], &Al[nb][w*512]);
            // reconstruct fp32 for the sat output write (natural k-group)
            u16x8 hv = *(const u16x8*)&hnH[(size_t)node*128 + col0 + sg*8];
            u16x8 lv = *(const u16x8*)&hnL[(size_t)node*128 + col0 + sg*8];
            float f[8];
#pragma unroll
            for (int j = 0; j < 8; ++j)
                f[j] = __uint_as_float(((unsigned)hv[j])<<16)
                     + __uint_as_float(((unsigned)lv[j])<<16);
            float4 v0 = {f[0],f[1],f[2],f[3]}, v1 = {f[4],f[5],f[6],f[7]};
            *(float4*)&sat[e*384 + kc + sg*8] = v0;
            *(float4*)&sat[e*384 + kc + sg*8 + 4] = v1;
        } else {
            const float* p = &sat[e*384 + kc + sg*8];   // w1 fp32 (written by k2)
            float4 v0 = *(const float4*)p, v1 = *(const float4*)(p+4);
            s8v hi, lo; split8(v0, v1, hi, lo);
            *(s8v*)&Ah[nb][aslot] = hi; *(s8v*)&Al[nb][aslot] = lo;
        }
    };
    stage(0, 0);
    __syncthreads();
    int cur = 0;
    for (int t = 0; t < 12; ++t){
        if (t+1 < 12) stage(cur^1, t+1);
        s8v ah = *(const s8v*)&Ah[cur][lds_a(w*16 + ls, lg)];
        s8v al = *(const s8v*)&Al[cur][lds_a(w*16 + ls, lg)];
#pragma unroll
        for (int ct = 0; ct < 8; ++ct){
            int c = ct*16 + ls;
            s8v bh = *(const s8v*)&Bh[cur][lds_a(c,lg)];
            s8v bl = *(const s8v*)&Bl[cur][lds_a(c,lg)];
            acc[ct] = MFMA16(ah, bh, acc[ct]);
            acc[ct] = MFMA16(ah, bl, acc[ct]);
            acc[ct] = MFMA16(al, bh, acc[ct]);
        }
        __syncthreads();
        cur ^= 1;
    }
    // epilogue: attn dot -> s; w2 = a * w1
#pragma unroll
    for (int reg = 0; reg < 4; ++reg){
        float p = 0.f;
#pragma unroll
        for (int ct = 0; ct < 8; ++ct){
            int col = ct*16 + ls;
            p += lrelu(acc[ct][reg] + sBf[col]) * sAtt[col];
        }
#pragma unroll
        for (int m = 1; m < 16; m <<= 1) p += __shfl_xor(p, m);
        long long orow = rbase + w*16 + lg*4 + reg;
        if (ls == 0) s_ws[orow] = p;
#pragma unroll
        for (int ct = 0; ct < 8; ++ct){
            int col = ct*16 + ls;
            float w1v = sat[orow*384 + 256 + col];
            w2[orow*128 + col] = p * w1v;
        }
    }
}

// ---------------- k5: per-node softmax + gather-aggregate ----------------
__global__ __launch_bounds__(TB) void k5_agg(const float* __restrict__ s,
                                             const unsigned short* __restrict__ hnH,
                                             const unsigned short* __restrict__ hnL,
                                             const float* __restrict__ w2,
                                             const int* __restrict__ src,
                                             const int* __restrict__ eidx,
                                             const int* __restrict__ offs,
                                             const int* __restrict__ cur,
                                             float* __restrict__ hagg,
                                             float* __restrict__ den){
    __shared__ int   sE[MAXD];
    __shared__ int   sSrc[MAXD];
    __shared__ float sA[MAXD];
    __shared__ float sh4[4];
    const int n = blockIdx.x, tid = threadIdx.x;
    const int start = offs[n];
    const int deg = cur[n] - start;
    for (int i = tid; i < deg && i < MAXD; i += TB) sE[i] = eidx[start+i];
    __syncthreads();
    if (tid == 0 && deg > 1){
        int dd = deg < MAXD ? deg : MAXD;
        for (int i = 1; i < dd; ++i){
            int key = sE[i], j = i-1;
            while (j >= 0 && sE[j] > key){ sE[j+1] = sE[j]; --j; }
            sE[j+1] = key;
        }
    }
    __syncthreads();
    float lm = -3.402823466e38f;
    for (int i = tid; i < deg; i += TB){
        int e = (i < MAXD) ? sE[i] : eidx[start+i];
        lm = fmaxf(lm, s[e]);
    }
    const float m = blockMax(lm, sh4);
    float lsum = 0.f;
    for (int i = tid; i < deg; i += TB){
        int e = (i < MAXD) ? sE[i] : eidx[start+i];
        lsum += expf(s[e] - m);
    }
    const float denom = blockSum(lsum, sh4);
    for (int i = tid; i < deg && i < MAXD; i += TB){
        int e = sE[i];
        sA[i] = expf(s[e] - m) / denom;
        sSrc[i] = src[e];
    }
    __syncthreads();
    float acc = 0.f;
    const bool lo = tid < 128;
    for (int i = 0; i < deg; ++i){
        int e, sI; float a;
        if (i < MAXD){ e = sE[i]; a = sA[i]; sI = sSrc[i]; }
        else { e = eidx[start+i]; a = expf(s[e]-m)/denom; sI = src[e]; }
        float v = lo ? bfpair(hnH[(size_t)sI*128 + tid], hnL[(size_t)sI*128 + tid])
                     : w2[(size_t)e*128 + (tid-128)];
        acc = fmaf(a, v, acc);
    }
    hagg[(size_t)n*256 + tid] = acc;
    if (tid == 0) den[n] = (deg > 0) ? denom : 0.f;
}

// ---------------- k6: h_new = [h_agg, hn] @ W_conc + b_conc ; indeg select ----------------
// also emits houtH/houtL (bf16 split) overlaid into the consumed hagg region
__global__ __launch_bounds__(TB) void k6_conc(const float* hagg,
                                              const unsigned short* __restrict__ hnH,
                                              const unsigned short* __restrict__ hnL,
                                              const float* __restrict__ Wc,
                                              const float* __restrict__ bc,
                                              const float* __restrict__ den,
                                              float* __restrict__ hout,
                                              unsigned short* houtHL){
    __shared__ float Ast[BK][ASTR];
    __shared__ float Bs[BK][BN];
    __shared__ float sBc[BN];
    const int tid = threadIdx.x;
    const int rbase = blockIdx.x * BM;
    const int tc = tid & 15, tr = tid >> 4;
    const int r0 = tr*4, c0 = tc*4;
    if (tid < BN) sBc[tid] = bc[tid];
    float acc[4][8] = {};
    for (int chunk = 0; chunk < 12; ++chunk){
        int kc = chunk * BK;
        __syncthreads();
        {
            int lr = tid >> 3, k4 = (tid & 7) << 2;
#pragma unroll
            for (int p = 0; p < 2; ++p){
                int r = p*32 + lr;
                int rr = rbase + r; if (rr >= NN) rr = NN-1;
                float4 v;
                if (chunk < 8) v = *(const float4*)&hagg[(size_t)rr*256 + kc + k4];
                else {
                    int cb = (kc - 256) + k4;
                    u16x4 hh = *(const u16x4*)&hnH[(size_t)rr*128 + cb];
                    u16x4 ll = *(const u16x4*)&hnL[(size_t)rr*128 + cb];
                    v.x = bfpair(hh[0], ll[0]); v.y = bfpair(hh[1], ll[1]);
                    v.z = bfpair(hh[2], ll[2]); v.w = bfpair(hh[3], ll[3]);
                }
                store_At(Ast, k4, r, v);
            }
        }
        load_B(Wc, kc, Bs, tid);
        __syncthreads();
        mm_chunk(Ast, Bs, r0, c0, acc);
    }
#pragma unroll
    for (int i = 0; i < 4; ++i){
        int rr = rbase + r0 + i;
        if (rr >= NN) continue;
        bool keep = den[rr] > 0.f;
        float o[8];
#pragma unroll
        for (int j = 0; j < 8; ++j){
            int col = (j < 4) ? (c0 + j) : (60 + c0 + j);
            float fb = bfpair(hnH[(size_t)rr*128 + col], hnL[(size_t)rr*128 + col]);
            o[j] = keep ? acc[i][j] + sBc[col] : fb;
        }
        float4 o0 = {o[0],o[1],o[2],o[3]}, o1 = {o[4],o[5],o[6],o[7]};
        *(float4*)&hout[(size_t)rr*128 + c0] = o0;
        *(float4*)&hout[(size_t)rr*128 + 64 + c0] = o1;
        u16x4 h0, l0, h1, l1;
#pragma unroll
        for (int j = 0; j < 4; ++j){
            unsigned short hs, ls2;
            split1(o[j], hs, ls2);   h0[j] = hs; l0[j] = ls2;
            split1(o[4+j], hs, ls2); h1[j] = hs; l1[j] = ls2;
        }
        *(u16x4*)&houtHL[(size_t)rr*512 + c0] = h0;
        *(u16x4*)&houtHL[(size_t)rr*512 + 128 + c0] = l0;
        *(u16x4*)&houtHL[(size_t)rr*512 + 64 + c0] = h1;
        *(u16x4*)&houtHL[(size_t)rr*512 + 128 + 64 + c0] = l1;
    }
}

// ---------------- k7: w_out = [h_out[src], h_out[dst], w_bn, ow] @ W_aggre ----------------
__global__ __launch_bounds__(TBM) void k7_mfma(const unsigned short* __restrict__ houtHL,
                                               const unsigned short* __restrict__ owH,
                                               const unsigned short* __restrict__ owL,
                                               const float* __restrict__ gamma,
                                               const float* __restrict__ beta,
                                               const unsigned short* __restrict__ wtH,
                                               const unsigned short* __restrict__ wtL,
                                               const int* __restrict__ src,
                                               const int* __restrict__ dst,
                                               float* __restrict__ w2out){
    __shared__ __align__(16) unsigned short Ah[2][4096], Al[2][4096], Bh[2][4096], Bl[2][4096];
    __shared__ float sGam[128], sBet[128];
    __shared__ int sSrc[128], sDst[128];
    const int tid = threadIdx.x;
    const long long rbase = (long long)blockIdx.x * 128;
    const int lane = tid & 63, w = tid >> 6;
    const int ls = lane & 15, lg = lane >> 4;
    const int srow = tid >> 2, sg = tid & 3;
    const int gsw = sg ^ (srow & 3);
    const int aslot = srow*32 + (gsw << 3);
    const float ISR = 0.9999950000374997f;  // 1/sqrt(1+1e-5)
    if (tid < 128){
        sGam[tid] = gamma[tid] * ISR; sBet[tid] = beta[tid];
        sSrc[tid] = src[rbase + tid]; sDst[tid] = dst[rbase + tid];
    }
    __syncthreads();   // sSrc/sDst/sGam/sBet used by stage
    f32x4 acc[8] = {};
    auto stage = [&](int nb, int t){
        const int kc = t*32;
        gl16(&wtH[srow*512 + kc + gsw*8], &Bh[nb][w*512]);
        gl16(&wtL[srow*512 + kc + gsw*8], &Bl[nb][w*512]);
        long long e = rbase + srow;
        if (kc < 256){
            int node = (kc < 128) ? sSrc[srow] : sDst[srow];
            int col0 = kc & 127;
            gl16(&houtHL[(size_t)node*512 + col0 + gsw*8], &Ah[nb][w*512]);
            gl16(&houtHL[(size_t)node*512 + 128 + col0 + gsw*8], &Al[nb][w*512]);
        } else if (kc < 384){
            int cb = (kc - 256) + sg*8;
            const float* p = &w2out[e*128 + cb];
            float4 v0 = *(const float4*)p, v1 = *(const float4*)(p+4);
            v0.x = fmaf(v0.x, sGam[cb+0], sBet[cb+0]);
            v0.y = fmaf(v0.y, sGam[cb+1], sBet[cb+1]);
            v0.z = fmaf(v0.z, sGam[cb+2], sBet[cb+2]);
            v0.w = fmaf(v0.w, sGam[cb+3], sBet[cb+3]);
            v1.x = fmaf(v1.x, sGam[cb+4], sBet[cb+4]);
            v1.y = fmaf(v1.y, sGam[cb+5], sBet[cb+5]);
            v1.z = fmaf(v1.z, sGam[cb+6], sBet[cb+6]);
            v1.w = fmaf(v1.w, sGam[cb+7], sBet[cb+7]);
            s8v hi, lo; split8(v0, v1, hi, lo);
            *(s8v*)&Ah[nb][aslot] = hi; *(s8v*)&Al[nb][aslot] = lo;
        } else {
            int col0 = kc - 384;
            gl16(&owH[e*128 + col0 + gsw*8], &Ah[nb][w*512]);
            gl16(&owL[e*128 + col0 + gsw*8], &Al[nb][w*512]);
        }
    };
    stage(0, 0);
    __syncthreads();
    int cur = 0;
    for (int t = 0; t < 16; ++t){
        if (t+1 < 16) stage(cur^1, t+1);
        s8v ah = *(const s8v*)&Ah[cur][lds_a(w*16 + ls, lg)];
        s8v al = *(const s8v*)&Al[cur][lds_a(w*16 + ls, lg)];
#pragma unroll
        for (int ct = 0; ct < 8; ++ct){
            int c = ct*16 + ls;
            s8v bh = *(const s8v*)&Bh[cur][lds_a(c,lg)];
            s8v bl = *(const s8v*)&Bl[cur][lds_a(c,lg)];
            acc[ct] = MFMA16(ah, bh, acc[ct]);
            acc[ct] = MFMA16(ah, bl, acc[ct]);
            acc[ct] = MFMA16(al, bh, acc[ct]);
        }
        __syncthreads();
        cur ^= 1;
    }
#pragma unroll
    for (int reg = 0; reg < 4; ++reg){
        long long orow = rbase + w*16 + lg*4 + reg;
#pragma unroll
        for (int ct = 0; ct < 8; ++ct)
            w2out[orow*128 + ct*16 + ls] = acc[ct][reg];
    }
}

extern "C" void kernel_launch(void* const* d_in, const int* in_sizes, int n_in,
                              void* d_out, int out_size, void* d_ws, size_t ws_size,
                              hipStream_t stream){
    (void)in_sizes; (void)n_in; (void)out_size;
    const float* h       = (const float*)d_in[0];
    const float* edge_w  = (const float*)d_in[1];
    const float* W_node  = (const float*)d_in[2];
    const float* W_eedge = (const float*)d_in[3];
    const float* W_esf   = (const float*)d_in[4];
    const float* W_fuse  = (const float*)d_in[5];
    const float* b_fuse  = (const float*)d_in[6];
    const float* W_attn  = (const float*)d_in[7];
    const float* W_conc  = (const float*)d_in[8];
    const float* b_conc  = (const float*)d_in[9];
    const float* gamma   = (const float*)d_in[10];
    const float* beta    = (const float*)d_in[11];
    const float* W_aggre = (const float*)d_in[12];
    const int*   src     = (const int*)d_in[13];
    const int*   dst     = (const int*)d_in[14];

    float* out    = (float*)d_out;
    float* o_hout = out + OUT_HOUT;
    float* o_wout = out + OUT_WOUT;
    float* o_sat  = out + OUT_SAT;

    if (ws_size < (size_t)WS_FLOATS * 4) return;
    float* ws     = (float*)d_ws;
    unsigned short* w_hnH = (unsigned short*)(ws + OFF_HN);
    unsigned short* w_hnL = w_hnH + (size_t)NN*128;
    unsigned short* w_owH = (unsigned short*)(ws + OFF_OW);
    unsigned short* w_owL = w_owH + (size_t)NE*128;
    float* w_s    = ws + OFF_S;
    float* w_den  = ws + OFF_DEN;
    int*   w_cur  = (int*)(ws + OFF_CUR);
    float* w_hagg = ws + OFF_HAGG;
    unsigned short* w_houtHL = (unsigned short*)w_hagg;   // overlaid post-k6
    unsigned short* w_wt = (unsigned short*)(ws + OFF_WT);

    int* w_eidx = (int*)o_hout;          // E ints (pre-k6 scratch)
    int* w_offs = w_eidx + NE;           // N ints

    hipLaunchKernelGGL(k_prep,    dim3(131072/TB), dim3(TB), 0, stream,
                       W_eedge, W_fuse, W_aggre, w_wt, w_cur);
    hipLaunchKernelGGL(kB_count,  dim3(NE/TB), dim3(TB), 0, stream, dst, w_cur);
    hipLaunchKernelGGL(kC_scan,   dim3(1), dim3(TB), 0, stream, w_cur, w_offs);
    hipLaunchKernelGGL(kD_scatter,dim3(NE/TB), dim3(TB), 0, stream, dst, w_cur, w_eidx);
    hipLaunchKernelGGL(k1_hn,     dim3((NN+BM-1)/BM), dim3(TB), 0, stream, h, W_node,
                       w_hnH, w_hnL);
    hipLaunchKernelGGL(k2_mfma,   dim3(NE/128), dim3(TBM), 0, stream, edge_w,
                       w_wt + U_E, w_wt + U_E + 128*128, W_esf,
                       w_owH, w_owL, o_sat);
    hipLaunchKernelGGL(k3_mfma,   dim3(NE/128), dim3(TBM), 0, stream, w_hnH, w_hnL,
                       w_wt + U_F, w_wt + U_F + 128*384, b_fuse, W_attn,
                       src, dst, o_sat, o_wout, w_s);
    hipLaunchKernelGGL(k5_agg,    dim3(NN), dim3(TB), 0, stream, w_s, w_hnH, w_hnL, o_wout,
                       src, w_eidx, w_offs, w_cur, w_hagg, w_den);
    hipLaunchKernelGGL(k6_conc,   dim3((NN+BM-1)/BM), dim3(TB), 0, stream, w_hagg,
                       w_hnH, w_hnL, W_conc, b_conc, w_den, o_hout, w_houtHL);
    hipLaunchKernelGGL(k7_mfma,   dim3(NE/128), dim3(TBM), 0, stream, w_houtHL,
                       w_owH, w_owL, gamma, beta,
                       w_wt + U_A, w_wt + U_A + 128*512,
                       src, dst, o_wout);
}

// Round 7
// 711.468 us; speedup vs baseline: 1.1727x; 1.1727x over previous
//
#include <hip/hip_runtime.h>
#include <hip/hip_bf16.h>

#define TB 256
#define TBM 512   // MFMA kernels: 8 waves/block
#define BM 64
#define BK 32
#define BN 128
#define ASTR 68   // BM + 4 (fp32 path, k6)
#define MAXD 160  // per-node edge cache for k5

static constexpr int NN = 20000;
static constexpr int NE = 320000;

// workspace layout (floats)
static constexpr long long OFF_HN   = 0;          // hnH/hnL bf16 split: NN*128 ushorts each
static constexpr long long OFF_OW   = 2560000;    // owH/owL bf16: E*128 ushort each
static constexpr long long OFF_S    = 43520000;   // E  (raw attention scalar s)
static constexpr long long OFF_DEN  = 43840000;   // N
static constexpr long long OFF_CUR  = 43860000;   // N ints
static constexpr long long OFF_HAGG = 43880000;   // N*256 fp32; post-k6 overlaid houtH/L (512-ushort row stride)
static constexpr long long OFF_WT   = 49000000;   // split-bf16 transposed weights (ushort)
static constexpr long long WS_FLOATS = 49140000;  // ~196.6 MB (proven budget)

// Wt sub-offsets in ushort units from OFF_WT base
static constexpr int U_E = 0;        // W_eedge^T hi [128][128]; lo at +16384
static constexpr int U_F = 32768;    // W_fuse^T  hi [128][384]; lo at +49152
static constexpr int U_A = 131072;   // W_aggre^T hi [128][512]; lo at +65536

// d_out layout (floats): h_out, w_out, sat
static constexpr long long OUT_HOUT = 0;
static constexpr long long OUT_WOUT = 2560000;    // holds hnP (packed u32) until k7 overwrites with w_out
static constexpr long long OUT_SAT  = 43520000;

typedef __attribute__((ext_vector_type(8))) short s8v;            // 8 bf16 (4 VGPR)
typedef __attribute__((ext_vector_type(4))) float f32x4;
typedef __attribute__((ext_vector_type(4))) unsigned short u16x4;

#define MFMA16(a,b,c) __builtin_amdgcn_mfma_f32_16x16x32_bf16(a,b,c,0,0,0)

__device__ __forceinline__ float lrelu(float x){ return x >= 0.f ? x : 0.1f*x; }

// async global->LDS, 16B per lane; LDS dest = wave-uniform base + lane*16
__device__ __forceinline__ void gl16(const void* g, void* l){
    __builtin_amdgcn_global_load_lds(
        (const __attribute__((address_space(1))) void*)g,
        (__attribute__((address_space(3))) void*)l, 16, 0, 0);
}

// ---- split fp32 -> (hi,lo) bf16, RNE both ----
__device__ __forceinline__ void split1(float f, unsigned short& hi, unsigned short& lo){
    __hip_bfloat16 h = __float2bfloat16(f);
    float hf = __bfloat162float(h);
    __hip_bfloat16 l = __float2bfloat16(f - hf);
    hi = __builtin_bit_cast(unsigned short, h);
    lo = __builtin_bit_cast(unsigned short, l);
}
__device__ __forceinline__ void split8(float4 a, float4 b, s8v& hi, s8v& lo){
    float v[8] = {a.x,a.y,a.z,a.w,b.x,b.y,b.z,b.w};
#pragma unroll
    for (int j = 0; j < 8; ++j){
        unsigned short hs, ls;
        split1(v[j], hs, ls);
        hi[j] = (short)hs; lo[j] = (short)ls;
    }
}
// packed u32 (hi<<16|lo) -> fp32
__device__ __forceinline__ float bfp(unsigned p){
    return __uint_as_float(p & 0xffff0000u) + __uint_as_float(p << 16);
}

// LDS tile addressing: [128 rows][32 k] bf16; slot g holds k-group g^(row&3)
__device__ __forceinline__ int lds_a(int row, int g){
    return row*32 + ((g ^ (row & 3)) << 3);   // ushort index, 16B aligned
}

// ================= fp32 helpers for k6 =================
__device__ __forceinline__ void store_At(float (*Ast)[ASTR], int k4, int r, float4 v){
    Ast[k4+0][r] = v.x; Ast[k4+1][r] = v.y; Ast[k4+2][r] = v.z; Ast[k4+3][r] = v.w;
}
__device__ __forceinline__ void mm_chunk(const float (*Ast)[ASTR], const float (*Bs)[BN],
                                         int r0, int c0, float acc[4][8]){
#pragma unroll 4
    for (int k = 0; k < BK; ++k){
        const float4 av = *(const float4*)&Ast[k][r0];
        const float4 b0 = *(const float4*)&Bs[k][c0];
        const float4 b1 = *(const float4*)&Bs[k][64 + c0];
        const float a0=av.x, a1=av.y, a2=av.z, a3=av.w;
        const float b[8] = {b0.x,b0.y,b0.z,b0.w,b1.x,b1.y,b1.z,b1.w};
#pragma unroll
        for (int j = 0; j < 8; ++j){
            acc[0][j] = fmaf(a0, b[j], acc[0][j]);
            acc[1][j] = fmaf(a1, b[j], acc[1][j]);
            acc[2][j] = fmaf(a2, b[j], acc[2][j]);
            acc[3][j] = fmaf(a3, b[j], acc[3][j]);
        }
    }
}
__device__ __forceinline__ void load_B(const float* __restrict__ W, int kc,
                                       float (*Bs)[BN], int tid){
#pragma unroll
    for (int p = 0; p < 4; ++p){
        int idx = p*TB + tid;
        int row = idx >> 5;
        int c4  = (idx & 31) << 2;
        *(float4*)&Bs[row][c4] = *(const float4*)&W[(size_t)(kc+row)*BN + c4];
    }
}

// ---------------- k_prep: cur init + all three weight transpose/splits ----------------
__global__ __launch_bounds__(TB) void k_prep(const float* __restrict__ We,
                                             const float* __restrict__ Wf,
                                             const float* __restrict__ Wa,
                                             unsigned short* __restrict__ wt,
                                             int* __restrict__ cur){
    int id = blockIdx.x*TB + threadIdx.x;   // grid covers 131072
    if (id < NN) cur[id] = 0;
    unsigned short hs, ls;
    if (id < 16384){                       // W_eedge: K=128
        int n = id >> 7, k = id & 127;
        split1(We[(size_t)k*128 + n], hs, ls);
        wt[U_E + id] = hs; wt[U_E + 16384 + id] = ls;
    } else if (id < 65536){                // W_fuse: K=384
        int local = id - 16384;
        int n = local / 384, k = local - n*384;
        split1(Wf[(size_t)k*128 + n], hs, ls);
        wt[U_F + local] = hs; wt[U_F + 49152 + local] = ls;
    } else if (id < 131072){               // W_aggre: K=512
        int local = id - 65536;
        int n = local >> 9, k = local & 511;
        split1(Wa[(size_t)k*128 + n], hs, ls);
        wt[U_A + local] = hs; wt[U_A + 65536 + local] = ls;
    }
}

// ---------------- sort pipeline ----------------
__global__ __launch_bounds__(TB) void kB_count(const int* __restrict__ dst,
                                               int* __restrict__ cur){
    int e = blockIdx.x*TB + threadIdx.x;
    atomicAdd(&cur[dst[e]], 1);
}
__global__ __launch_bounds__(TB) void kC_scan(int* __restrict__ cur,
                                              int* __restrict__ offs){
    __shared__ int part[TB];
    __shared__ int spre[TB];
    const int tid = threadIdx.x;
    const int CH = (NN + TB - 1) / TB;
    const int base = tid * CH;
    int sum = 0;
    for (int i = 0; i < CH; ++i){ int idx = base + i; if (idx < NN) sum += cur[idx]; }
    part[tid] = sum;
    __syncthreads();
    if (tid == 0){ int r = 0; for (int i = 0; i < TB; ++i){ spre[i] = r; r += part[i]; } }
    __syncthreads();
    int run = spre[tid];
    for (int i = 0; i < CH; ++i){
        int idx = base + i;
        if (idx < NN){ int c = cur[idx]; offs[idx] = run; cur[idx] = run; run += c; }
    }
}
__global__ __launch_bounds__(TB) void kD_scatter(const int* __restrict__ dst,
                                                 int* __restrict__ cur,
                                                 int* __restrict__ eidx){
    int e = blockIdx.x*TB + threadIdx.x;
    int p = atomicAdd(&cur[dst[e]], 1);
    eidx[p] = e;
}

// ---------------- k1: hn = h @ W_node (fp32 GEMM; outputs hnH/hnL split + hnP packed) ----------------
__global__ __launch_bounds__(TB) void k1_hn(const float* __restrict__ h,
                                            const float* __restrict__ Wn,
                                            unsigned short* __restrict__ hnH,
                                            unsigned short* __restrict__ hnL,
                                            unsigned* __restrict__ hnP){
    __shared__ float Ast[BK][ASTR];
    __shared__ float Bs[BK][BN];
    const int tid = threadIdx.x;
    const int rbase = blockIdx.x * BM;
    const int tc = tid & 15, tr = tid >> 4;
    const int r0 = tr*4, c0 = tc*4;
    float acc[4][8] = {};
    for (int kc = 0; kc < 128; kc += BK){
        __syncthreads();
        {
            int lr = tid >> 3, k4 = (tid & 7) << 2;
#pragma unroll
            for (int p = 0; p < 2; ++p){
                int r = p*32 + lr;
                int rr = rbase + r; if (rr >= NN) rr = NN-1;
                float4 v = *(const float4*)&h[(size_t)rr*128 + kc + k4];
                store_At(Ast, k4, r, v);
            }
        }
        load_B(Wn, kc, Bs, tid);
        __syncthreads();
        mm_chunk(Ast, Bs, r0, c0, acc);
    }
#pragma unroll
    for (int i = 0; i < 4; ++i){
        int rr = rbase + r0 + i;
        if (rr < NN){
            u16x4 h0, l0, h1, l1;
            uint4 p0, p1;
#pragma unroll
            for (int j = 0; j < 4; ++j){
                unsigned short hs, ls;
                split1(acc[i][j], hs, ls);
                h0[j] = hs; l0[j] = ls;
                ((unsigned*)&p0)[j] = ((unsigned)hs << 16) | ls;
                split1(acc[i][4+j], hs, ls);
                h1[j] = hs; l1[j] = ls;
                ((unsigned*)&p1)[j] = ((unsigned)hs << 16) | ls;
            }
            *(u16x4*)&hnH[(size_t)rr*128 + c0] = h0;
            *(u16x4*)&hnL[(size_t)rr*128 + c0] = l0;
            *(u16x4*)&hnH[(size_t)rr*128 + 64 + c0] = h1;
            *(u16x4*)&hnL[(size_t)rr*128 + 64 + c0] = l1;
            *(uint4*)&hnP[(size_t)rr*128 + c0] = p0;
            *(uint4*)&hnP[(size_t)rr*128 + 64 + c0] = p1;
        }
    }
}

// ================== MFMA split-bf16 edge GEMMs: 512 thr, 8 waves, 128x128 tile ==================

// ---------------- k2: ow = edge_w @ W_eedge ; w1 = (lrelu(ow)@W_esf)*ow ----------------
__global__ __launch_bounds__(TBM) void k2_mfma(const float* __restrict__ ew,
                                               const unsigned short* __restrict__ wtH,
                                               const unsigned short* __restrict__ wtL,
                                               const float* __restrict__ Wesf,
                                               unsigned short* __restrict__ owH,
                                               unsigned short* __restrict__ owL,
                                               float* __restrict__ sat){
    __shared__ __align__(16) unsigned short Ah[2][4096], Al[2][4096], Bh[2][4096], Bl[2][4096];
    __shared__ float sEsf[128];
    const int tid = threadIdx.x;
    const long long rbase = (long long)blockIdx.x * 128;
    const int lane = tid & 63, w = tid >> 6;
    const int ls = lane & 15, lg = lane >> 4;
    const int srow = tid >> 2, sg = tid & 3;
    const int gsw = sg ^ (srow & 3);
    const int aslot = srow*32 + (gsw << 3);
    if (tid < 128) sEsf[tid] = Wesf[tid];
    f32x4 acc[8] = {};
    auto stage = [&](int nb, int t){
        const int kc = t*32;
        gl16(&wtH[srow*128 + kc + gsw*8], &Bh[nb][w*512]);
        gl16(&wtL[srow*128 + kc + gsw*8], &Bl[nb][w*512]);
        const float* p = &ew[(rbase + srow)*128 + kc + sg*8];
        float4 v0 = *(const float4*)p, v1 = *(const float4*)(p+4);
        s8v hi, lo; split8(v0, v1, hi, lo);
        *(s8v*)&Ah[nb][aslot] = hi; *(s8v*)&Al[nb][aslot] = lo;
    };
    stage(0, 0);
    __syncthreads();
    int cur = 0;
    for (int t = 0; t < 4; ++t){
        if (t+1 < 4) stage(cur^1, t+1);
        s8v ah = *(const s8v*)&Ah[cur][lds_a(w*16 + ls, lg)];
        s8v al = *(const s8v*)&Al[cur][lds_a(w*16 + ls, lg)];
#pragma unroll
        for (int ct = 0; ct < 8; ++ct){
            int c = ct*16 + ls;
            s8v bh = *(const s8v*)&Bh[cur][lds_a(c,lg)];
            s8v bl = *(const s8v*)&Bl[cur][lds_a(c,lg)];
            acc[ct] = MFMA16(ah, bh, acc[ct]);
            acc[ct] = MFMA16(ah, bl, acc[ct]);
            acc[ct] = MFMA16(al, bh, acc[ct]);
        }
        __syncthreads();
        cur ^= 1;
    }
#pragma unroll
    for (int reg = 0; reg < 4; ++reg){
        float p = 0.f;
#pragma unroll
        for (int ct = 0; ct < 8; ++ct)
            p += lrelu(acc[ct][reg]) * sEsf[ct*16 + ls];
#pragma unroll
        for (int m = 1; m < 16; m <<= 1) p += __shfl_xor(p, m);
        long long orow = rbase + w*16 + lg*4 + reg;
#pragma unroll
        for (int ct = 0; ct < 8; ++ct){
            float o = acc[ct][reg];
            int col = ct*16 + ls;
            sat[orow*384 + 256 + col] = p * o;
            unsigned short hs_, ls_; split1(o, hs_, ls_);
            owH[orow*128 + col] = hs_;
            owL[orow*128 + col] = ls_;
        }
    }
}

// ---------------- k3: sat build + inw GEMM + attn dot -> s (w2 eliminated) ----------------
__global__ __launch_bounds__(TBM) void k3_mfma(const unsigned short* __restrict__ hnH,
                                               const unsigned short* __restrict__ hnL,
                                               const unsigned* __restrict__ hnP,
                                               const unsigned short* __restrict__ wtH,
                                               const unsigned short* __restrict__ wtL,
                                               const float* __restrict__ bf,
                                               const float* __restrict__ Wattn,
                                               const int* __restrict__ src,
                                               const int* __restrict__ dst,
                                               float* __restrict__ sat,
                                               float* __restrict__ s_ws){
    __shared__ __align__(16) unsigned short Ah[2][4096], Al[2][4096], Bh[2][4096], Bl[2][4096];
    __shared__ float sBf[128], sAtt[128];
    __shared__ int sSrc[128], sDst[128];
    const int tid = threadIdx.x;
    const long long rbase = (long long)blockIdx.x * 128;
    const int lane = tid & 63, w = tid >> 6;
    const int ls = lane & 15, lg = lane >> 4;
    const int srow = tid >> 2, sg = tid & 3;
    const int gsw = sg ^ (srow & 3);
    const int aslot = srow*32 + (gsw << 3);
    if (tid < 128){
        sBf[tid] = bf[tid]; sAtt[tid] = Wattn[tid];
        sSrc[tid] = src[rbase + tid]; sDst[tid] = dst[rbase + tid];
    }
    __syncthreads();   // sSrc/sDst used by stage
    f32x4 acc[8] = {};
    auto stage = [&](int nb, int t){
        const int kc = t*32;
        gl16(&wtH[srow*384 + kc + gsw*8], &Bh[nb][w*512]);
        gl16(&wtL[srow*384 + kc + gsw*8], &Bl[nb][w*512]);
        long long e = rbase + srow;
        if (kc < 256){
            int node = (kc < 128) ? sSrc[srow] : sDst[srow];
            int col0 = kc & 127;
            gl16(&hnH[(size_t)node*128 + col0 + gsw*8], &Ah[nb][w*512]);
            gl16(&hnL[(size_t)node*128 + col0 + gsw*8], &Al[nb][w*512]);
            // reconstruct fp32 for the sat output write (natural k-group)
            const unsigned* pp = &hnP[(size_t)node*128 + col0 + sg*8];
            uint4 q0 = *(const uint4*)pp, q1 = *(const uint4*)(pp+4);
            float4 v0 = {bfp(q0.x), bfp(q0.y), bfp(q0.z), bfp(q0.w)};
            float4 v1 = {bfp(q1.x), bfp(q1.y), bfp(q1.z), bfp(q1.w)};
            *(float4*)&sat[e*384 + kc + sg*8] = v0;
            *(float4*)&sat[e*384 + kc + sg*8 + 4] = v1;
        } else {
            const float* p = &sat[e*384 + kc + sg*8];   // w1 fp32 (written by k2)
            float4 v0 = *(const float4*)p, v1 = *(const float4*)(p+4);
            s8v hi, lo; split8(v0, v1, hi, lo);
            *(s8v*)&Ah[nb][aslot] = hi; *(s8v*)&Al[nb][aslot] = lo;
        }
    };
    stage(0, 0);
    __syncthreads();
    int cur = 0;
    for (int t = 0; t < 12; ++t){
        if (t+1 < 12) stage(cur^1, t+1);
        s8v ah = *(const s8v*)&Ah[cur][lds_a(w*16 + ls, lg)];
        s8v al = *(const s8v*)&Al[cur][lds_a(w*16 + ls, lg)];
#pragma unroll
        for (int ct = 0; ct < 8; ++ct){
            int c = ct*16 + ls;
            s8v bh = *(const s8v*)&Bh[cur][lds_a(c,lg)];
            s8v bl = *(const s8v*)&Bl[cur][lds_a(c,lg)];
            acc[ct] = MFMA16(ah, bh, acc[ct]);
            acc[ct] = MFMA16(ah, bl, acc[ct]);
            acc[ct] = MFMA16(al, bh, acc[ct]);
        }
        __syncthreads();
        cur ^= 1;
    }
    // epilogue: attn dot -> s only
#pragma unroll
    for (int reg = 0; reg < 4; ++reg){
        float p = 0.f;
#pragma unroll
        for (int ct = 0; ct < 8; ++ct){
            int col = ct*16 + ls;
            p += lrelu(acc[ct][reg] + sBf[col]) * sAtt[col];
        }
#pragma unroll
        for (int m = 1; m < 16; m <<= 1) p += __shfl_xor(p, m);
        if (ls == 0) s_ws[rbase + w*16 + lg*4 + reg] = p;
    }
}

// ---------------- k5: wave-per-node softmax + gather-aggregate (4 nodes/block) ----------------
__global__ __launch_bounds__(TB) void k5_agg(const float* __restrict__ s,
                                             const unsigned* __restrict__ hnP,
                                             const float* __restrict__ sat,
                                             const int* __restrict__ src,
                                             const int* __restrict__ eidx,
                                             const int* __restrict__ offs,
                                             const int* __restrict__ cur,
                                             float* __restrict__ hagg,
                                             float* __restrict__ den){
    __shared__ int   sEu[4][MAXD];   // unsorted ids -> (after sort) src ids
    __shared__ int   sEs[4][MAXD];   // sorted edge ids
    __shared__ float sAl[4][MAXD];   // ev -> alpha
    __shared__ float sWc[4][MAXD];   // raw s -> alpha*s
    const int wv = threadIdx.x >> 6, lane = threadIdx.x & 63;
    const int n = blockIdx.x*4 + wv;          // grid = NN/4 exactly
    int* Eu = sEu[wv]; int* Es = sEs[wv];
    float* Al = sAl[wv]; float* Wc = sWc[wv];
    const int start = offs[n];
    const int deg = cur[n] - start;
    const int dc = deg < MAXD ? deg : MAXD;
    for (int i = lane; i < dc; i += 64) Eu[i] = eidx[start+i];
    __syncthreads();
    // parallel rank sort (edge ids unique -> bijective)
    for (int i = lane; i < dc; i += 64){
        int my = Eu[i], r = 0;
        for (int j = 0; j < dc; ++j) r += (Eu[j] < my);
        Es[r] = my;
    }
    __syncthreads();
    // pass1: raw s -> Wc, src -> Eu (overwrite), wave max
    float lm = -3.402823466e38f;
    for (int i = lane; i < dc; i += 64){
        int e = Es[i];
        float sv = s[e];
        Wc[i] = sv;
        Eu[i] = src[e];
        lm = fmaxf(lm, sv);
    }
    for (int i = MAXD + lane; i < deg; i += 64) lm = fmaxf(lm, s[eidx[start+i]]);
#pragma unroll
    for (int m2 = 32; m2; m2 >>= 1) lm = fmaxf(lm, __shfl_xor(lm, m2));
    const float m = lm;
    // pass2: ev -> Al, wave sum
    float lsum = 0.f;
    for (int i = lane; i < dc; i += 64){
        float ev = expf(Wc[i] - m);
        Al[i] = ev;
        lsum += ev;
    }
    for (int i = MAXD + lane; i < deg; i += 64) lsum += expf(s[eidx[start+i]] - m);
#pragma unroll
    for (int m2 = 32; m2; m2 >>= 1) lsum += __shfl_xor(lsum, m2);
    const float denom = lsum;
    const float inv = (deg > 0) ? 1.f/denom : 0.f;
    // pass3: alpha, alpha*s
    for (int i = lane; i < dc; i += 64){
        float al = Al[i] * inv;
        Al[i] = al;
        Wc[i] = al * Wc[i];
    }
    __syncthreads();
    // accumulate: lane owns cols {lane, 64+lane} of hn-part and of w1-part (4 MLP streams)
    float a0=0.f, a1=0.f, a2=0.f, a3=0.f;
    for (int i = 0; i < dc; ++i){
        int sI = Eu[i];
        size_t e = (size_t)Es[i];
        float al = Al[i], wc = Wc[i];
        unsigned p0 = hnP[(size_t)sI*128 + lane];
        unsigned p1 = hnP[(size_t)sI*128 + 64 + lane];
        float w0 = sat[e*384 + 256 + lane];
        float w1v = sat[e*384 + 256 + 64 + lane];
        a0 = fmaf(al, bfp(p0), a0);
        a1 = fmaf(al, bfp(p1), a1);
        a2 = fmaf(wc, w0, a2);
        a3 = fmaf(wc, w1v, a3);
    }
    for (int i = MAXD; i < deg; ++i){            // tail: statistically never
        int e = eidx[start+i];
        float sv = s[e];
        float al = expf(sv - m) * inv;
        float wc = al * sv;
        int sI = src[e];
        a0 = fmaf(al, bfp(hnP[(size_t)sI*128 + lane]), a0);
        a1 = fmaf(al, bfp(hnP[(size_t)sI*128 + 64 + lane]), a1);
        a2 = fmaf(wc, sat[(size_t)e*384 + 256 + lane], a2);
        a3 = fmaf(wc, sat[(size_t)e*384 + 256 + 64 + lane], a3);
    }
    const size_t b = (size_t)n*256;
    hagg[b + lane] = a0;
    hagg[b + 64 + lane] = a1;
    hagg[b + 128 + lane] = a2;
    hagg[b + 192 + lane] = a3;
    if (lane == 0) den[n] = (deg > 0) ? denom : 0.f;
}

// ---------------- k6: h_new = [h_agg, hn] @ W_conc + b_conc ; indeg select ----------------
__global__ __launch_bounds__(TB) void k6_conc(const float* hagg,
                                              const unsigned* __restrict__ hnP,
                                              const float* __restrict__ Wc,
                                              const float* __restrict__ bc,
                                              const float* __restrict__ den,
                                              float* __restrict__ hout,
                                              unsigned short* houtHL){
    __shared__ float Ast[BK][ASTR];
    __shared__ float Bs[BK][BN];
    __shared__ float sBc[BN];
    const int tid = threadIdx.x;
    const int rbase = blockIdx.x * BM;
    const int tc = tid & 15, tr = tid >> 4;
    const int r0 = tr*4, c0 = tc*4;
    if (tid < BN) sBc[tid] = bc[tid];
    float acc[4][8] = {};
    for (int chunk = 0; chunk < 12; ++chunk){
        int kc = chunk * BK;
        __syncthreads();
        {
            int lr = tid >> 3, k4 = (tid & 7) << 2;
#pragma unroll
            for (int p = 0; p < 2; ++p){
                int r = p*32 + lr;
                int rr = rbase + r; if (rr >= NN) rr = NN-1;
                float4 v;
                if (chunk < 8) v = *(const float4*)&hagg[(size_t)rr*256 + kc + k4];
                else {
                    int cb = (kc - 256) + k4;
                    uint4 q = *(const uint4*)&hnP[(size_t)rr*128 + cb];
                    v.x = bfp(q.x); v.y = bfp(q.y); v.z = bfp(q.z); v.w = bfp(q.w);
                }
                store_At(Ast, k4, r, v);
            }
        }
        load_B(Wc, kc, Bs, tid);
        __syncthreads();
        mm_chunk(Ast, Bs, r0, c0, acc);
    }
#pragma unroll
    for (int i = 0; i < 4; ++i){
        int rr = rbase + r0 + i;
        if (rr >= NN) continue;
        bool keep = den[rr] > 0.f;
        float o[8];
#pragma unroll
        for (int j = 0; j < 8; ++j){
            int col = (j < 4) ? (c0 + j) : (60 + c0 + j);
            float fb = bfp(hnP[(size_t)rr*128 + col]);
            o[j] = keep ? acc[i][j] + sBc[col] : fb;
        }
        float4 o0 = {o[0],o[1],o[2],o[3]}, o1 = {o[4],o[5],o[6],o[7]};
        *(float4*)&hout[(size_t)rr*128 + c0] = o0;
        *(float4*)&hout[(size_t)rr*128 + 64 + c0] = o1;
        u16x4 h0, l0, h1, l1;
#pragma unroll
        for (int j = 0; j < 4; ++j){
            unsigned short hs, ls2;
            split1(o[j], hs, ls2);   h0[j] = hs; l0[j] = ls2;
            split1(o[4+j], hs, ls2); h1[j] = hs; l1[j] = ls2;
        }
        *(u16x4*)&houtHL[(size_t)rr*512 + c0] = h0;
        *(u16x4*)&houtHL[(size_t)rr*512 + 128 + c0] = l0;
        *(u16x4*)&houtHL[(size_t)rr*512 + 64 + c0] = h1;
        *(u16x4*)&houtHL[(size_t)rr*512 + 128 + 64 + c0] = l1;
    }
}

// ---------------- k7: w_out = [h_out[src], h_out[dst], w_bn, ow] @ W_aggre ----------------
// w_bn = (s_e * w1) * gamma/sqrt(1+eps) + beta, recomputed from sat + s (no w2 buffer)
__global__ __launch_bounds__(TBM) void k7_mfma(const unsigned short* __restrict__ houtHL,
                                               const unsigned short* __restrict__ owH,
                                               const unsigned short* __restrict__ owL,
                                               const float* __restrict__ sarr,
                                               const float* __restrict__ sat,
                                               const float* __restrict__ gamma,
                                               const float* __restrict__ beta,
                                               const unsigned short* __restrict__ wtH,
                                               const unsigned short* __restrict__ wtL,
                                               const int* __restrict__ src,
                                               const int* __restrict__ dst,
                                               float* __restrict__ w2out){
    __shared__ __align__(16) unsigned short Ah[2][4096], Al[2][4096], Bh[2][4096], Bl[2][4096];
    __shared__ float sGam[128], sBet[128], sS[128];
    __shared__ int sSrc[128], sDst[128];
    const int tid = threadIdx.x;
    const long long rbase = (long long)blockIdx.x * 128;
    const int lane = tid & 63, w = tid >> 6;
    const int ls = lane & 15, lg = lane >> 4;
    const int srow = tid >> 2, sg = tid & 3;
    const int gsw = sg ^ (srow & 3);
    const int aslot = srow*32 + (gsw << 3);
    const float ISR = 0.9999950000374997f;  // 1/sqrt(1+1e-5)
    if (tid < 128){
        sGam[tid] = gamma[tid] * ISR; sBet[tid] = beta[tid];
        sSrc[tid] = src[rbase + tid]; sDst[tid] = dst[rbase + tid];
        sS[tid] = sarr[rbase + tid];
    }
    __syncthreads();   // shared tables used by stage
    f32x4 acc[8] = {};
    auto stage = [&](int nb, int t){
        const int kc = t*32;
        gl16(&wtH[srow*512 + kc + gsw*8], &Bh[nb][w*512]);
        gl16(&wtL[srow*512 + kc + gsw*8], &Bl[nb][w*512]);
        long long e = rbase + srow;
        if (kc < 256){
            int node = (kc < 128) ? sSrc[srow] : sDst[srow];
            int col0 = kc & 127;
            gl16(&houtHL[(size_t)node*512 + col0 + gsw*8], &Ah[nb][w*512]);
            gl16(&houtHL[(size_t)node*512 + 128 + col0 + gsw*8], &Al[nb][w*512]);
        } else if (kc < 384){
            int cb = (kc - 256) + sg*8;
            float se = sS[srow];
            const float* p = &sat[e*384 + 256 + cb];   // w1
            float4 v0 = *(const float4*)p, v1 = *(const float4*)(p+4);
            v0.x = fmaf(v0.x*se, sGam[cb+0], sBet[cb+0]);
            v0.y = fmaf(v0.y*se, sGam[cb+1], sBet[cb+1]);
            v0.z = fmaf(v0.z*se, sGam[cb+2], sBet[cb+2]);
            v0.w = fmaf(v0.w*se, sGam[cb+3], sBet[cb+3]);
            v1.x = fmaf(v1.x*se, sGam[cb+4], sBet[cb+4]);
            v1.y = fmaf(v1.y*se, sGam[cb+5], sBet[cb+5]);
            v1.z = fmaf(v1.z*se, sGam[cb+6], sBet[cb+6]);
            v1.w = fmaf(v1.w*se, sGam[cb+7], sBet[cb+7]);
            s8v hi, lo; split8(v0, v1, hi, lo);
            *(s8v*)&Ah[nb][aslot] = hi; *(s8v*)&Al[nb][aslot] = lo;
        } else {
            int col0 = kc - 384;
            gl16(&owH[e*128 + col0 + gsw*8], &Ah[nb][w*512]);
            gl16(&owL[e*128 + col0 + gsw*8], &Al[nb][w*512]);
        }
    };
    stage(0, 0);
    __syncthreads();
    int cur = 0;
    for (int t = 0; t < 16; ++t){
        if (t+1 < 16) stage(cur^1, t+1);
        s8v ah = *(const s8v*)&Ah[cur][lds_a(w*16 + ls, lg)];
        s8v al = *(const s8v*)&Al[cur][lds_a(w*16 + ls, lg)];
#pragma unroll
        for (int ct = 0; ct < 8; ++ct){
            int c = ct*16 + ls;
            s8v bh = *(const s8v*)&Bh[cur][lds_a(c,lg)];
            s8v bl = *(const s8v*)&Bl[cur][lds_a(c,lg)];
            acc[ct] = MFMA16(ah, bh, acc[ct]);
            acc[ct] = MFMA16(ah, bl, acc[ct]);
            acc[ct] = MFMA16(al, bh, acc[ct]);
        }
        __syncthreads();
        cur ^= 1;
    }
#pragma unroll
    for (int reg = 0; reg < 4; ++reg){
        long long orow = rbase + w*16 + lg*4 + reg;
#pragma unroll
        for (int ct = 0; ct < 8; ++ct)
            w2out[orow*128 + ct*16 + ls] = acc[ct][reg];
    }
}

extern "C" void kernel_launch(void* const* d_in, const int* in_sizes, int n_in,
                              void* d_out, int out_size, void* d_ws, size_t ws_size,
                              hipStream_t stream){
    (void)in_sizes; (void)n_in; (void)out_size;
    const float* h       = (const float*)d_in[0];
    const float* edge_w  = (const float*)d_in[1];
    const float* W_node  = (const float*)d_in[2];
    const float* W_eedge = (const float*)d_in[3];
    const float* W_esf   = (const float*)d_in[4];
    const float* W_fuse  = (const float*)d_in[5];
    const float* b_fuse  = (const float*)d_in[6];
    const float* W_attn  = (const float*)d_in[7];
    const float* W_conc  = (const float*)d_in[8];
    const float* b_conc  = (const float*)d_in[9];
    const float* gamma   = (const float*)d_in[10];
    const float* beta    = (const float*)d_in[11];
    const float* W_aggre = (const float*)d_in[12];
    const int*   src     = (const int*)d_in[13];
    const int*   dst     = (const int*)d_in[14];

    float* out    = (float*)d_out;
    float* o_hout = out + OUT_HOUT;
    float* o_wout = out + OUT_WOUT;
    float* o_sat  = out + OUT_SAT;

    if (ws_size < (size_t)WS_FLOATS * 4) return;
    float* ws     = (float*)d_ws;
    unsigned short* w_hnH = (unsigned short*)(ws + OFF_HN);
    unsigned short* w_hnL = w_hnH + (size_t)NN*128;
    unsigned short* w_owH = (unsigned short*)(ws + OFF_OW);
    unsigned short* w_owL = w_owH + (size_t)NE*128;
    float* w_s    = ws + OFF_S;
    float* w_den  = ws + OFF_DEN;
    int*   w_cur  = (int*)(ws + OFF_CUR);
    float* w_hagg = ws + OFF_HAGG;
    unsigned short* w_houtHL = (unsigned short*)w_hagg;   // overlaid post-k6
    unsigned short* w_wt = (unsigned short*)(ws + OFF_WT);

    unsigned* w_hnP = (unsigned*)o_wout;  // packed hn in w_out region (free until k7)
    int* w_eidx = (int*)o_hout;           // E ints (pre-k6 scratch)
    int* w_offs = w_eidx + NE;            // N ints

    hipLaunchKernelGGL(k_prep,    dim3(131072/TB), dim3(TB), 0, stream,
                       W_eedge, W_fuse, W_aggre, w_wt, w_cur);
    hipLaunchKernelGGL(kB_count,  dim3(NE/TB), dim3(TB), 0, stream, dst, w_cur);
    hipLaunchKernelGGL(kC_scan,   dim3(1), dim3(TB), 0, stream, w_cur, w_offs);
    hipLaunchKernelGGL(kD_scatter,dim3(NE/TB), dim3(TB), 0, stream, dst, w_cur, w_eidx);
    hipLaunchKernelGGL(k1_hn,     dim3((NN+BM-1)/BM), dim3(TB), 0, stream, h, W_node,
                       w_hnH, w_hnL, w_hnP);
    hipLaunchKernelGGL(k2_mfma,   dim3(NE/128), dim3(TBM), 0, stream, edge_w,
                       w_wt + U_E, w_wt + U_E + 128*128, W_esf,
                       w_owH, w_owL, o_sat);
    hipLaunchKernelGGL(k3_mfma,   dim3(NE/128), dim3(TBM), 0, stream, w_hnH, w_hnL, w_hnP,
                       w_wt + U_F, w_wt + U_F + 128*384, b_fuse, W_attn,
                       src, dst, o_sat, w_s);
    hipLaunchKernelGGL(k5_agg,    dim3(NN/4), dim3(TB), 0, stream, w_s, w_hnP, o_sat,
                       src, w_eidx, w_offs, w_cur, w_hagg, w_den);
    hipLaunchKernelGGL(k6_conc,   dim3((NN+BM-1)/BM), dim3(TB), 0, stream, w_hagg,
                       w_hnP, W_conc, b_conc, w_den, o_hout, w_houtHL);
    hipLaunchKernelGGL(k7_mfma,   dim3(NE/128), dim3(TBM), 0, stream, w_houtHL,
                       w_owH, w_owL, w_s, o_sat, gamma, beta,
                       w_wt + U_A, w_wt + U_A + 128*512,
                       src, dst, o_wout);
}